// Round 7
// baseline (2067.340 us; speedup 1.0000x reference)
//
#include <hip/hip_runtime.h>

// BitNet MLP: out = (silu(x@Gw^T * gs) * (x@Uw^T * us)) @ Dw^T * ds
// M=4096 tokens, K=4096 hidden, I=11008 inter. Ternary weights -> exact in bf16.
// R7: weight cvt kernels ELIMINATED. fp32->bf16 fused into GEMM B-tile staging:
// ternary fp32 has zero low-mantissa bits -> truncation exact -> v_perm_b32
// packs 2 f32 -> 2 bf16. B staged via global_load_dwordx4 + perm + ds_write_b128
// (same XOR-swizzled layout, conflicts stay 0); A keeps global_load_lds.
// Saves ~350us of cvt time + halves weight HBM traffic (4B/elem once vs 8).

typedef short short8 __attribute__((ext_vector_type(8)));
typedef float f32x4 __attribute__((ext_vector_type(4)));
typedef float fvec4 __attribute__((ext_vector_type(4)));
typedef unsigned short usvec4 __attribute__((ext_vector_type(4)));
typedef unsigned int u32x4 __attribute__((ext_vector_type(4)));

#define BM 128
#define BK 32

__device__ __forceinline__ unsigned short f2bf(float f) {
    unsigned int u = __float_as_uint(f);
    u += 0x7FFFu + ((u >> 16) & 1u);   // round-to-nearest-even
    return (unsigned short)(u >> 16);
}

// x -> bf16 (needs RNE: x is arbitrary normal data). ~50MB, ~10us.
__global__ void cvt_f32_bf16(const fvec4* __restrict__ src,
                             usvec4* __restrict__ dst, long n4) {
    long i = (long)blockIdx.x * blockDim.x + threadIdx.x;
    if (i < n4) {
        fvec4 v = __builtin_nontemporal_load(src + i);
        usvec4 o;
        o.x = f2bf(v.x); o.y = f2bf(v.y); o.z = f2bf(v.z); o.w = f2bf(v.w);
        dst[i] = o;
    }
}

// 8 fp32 -> 8 bf16 by truncation (exact for ternary weights).
// v_perm_b32: dst = (S1.hi16) | (S0.hi16 << 16); builtin args are (S0, S1, sel).
__device__ __forceinline__ u32x4 pack_bf16x8(fvec4 a, fvec4 b) {
    union { fvec4 f; u32x4 u; } ua, ub;
    ua.f = a; ub.f = b;
    u32x4 r;
    r.x = __builtin_amdgcn_perm(ua.u.y, ua.u.x, 0x07060302u);
    r.y = __builtin_amdgcn_perm(ua.u.w, ua.u.z, 0x07060302u);
    r.z = __builtin_amdgcn_perm(ub.u.y, ub.u.x, 0x07060302u);
    r.w = __builtin_amdgcn_perm(ub.u.w, ub.u.z, 0x07060302u);
    return r;
}

#define GLOBAL_TO_LDS(gp, lp)                                                  \
    __builtin_amdgcn_global_load_lds(                                          \
        (__attribute__((address_space(1))) const void*)(gp),                   \
        (__attribute__((address_space(3))) void*)(lp), 16, 0, 0)

// stage one fp32 weight-tile granule pair into bf16 LDS (XOR-swizzled layout)
#define STAGE_W_TILE(Wf, lds)                                                  \
    do {                                                                       \
        const float* p0_ = (Wf) + (size_t)r0 * K + (k0 + kc0);                 \
        const float* p1_ = (Wf) + (size_t)r1 * K + (k0 + kc1);                 \
        fvec4 a0_ = *(const fvec4*)p0_, a1_ = *(const fvec4*)(p0_ + 4);        \
        fvec4 b0_ = *(const fvec4*)p1_, b1_ = *(const fvec4*)(p1_ + 4);        \
        *(u32x4*)(&(lds)[c0 * 8]) = pack_bf16x8(a0_, a1_);                     \
        *(u32x4*)(&(lds)[c1 * 8]) = pack_bf16x8(b0_, b1_);                     \
    } while (0)

// Fused gate/up GEMM + SwiGLU. A=[M][K] bf16 (LDS-DMA), Gw/Uw=[rows][K] fp32
// converted inline during staging. Writes inter[M][I] bf16.
__global__ __launch_bounds__(256, 2)
void gemm1_swiglu(const unsigned short* __restrict__ Xb,
                  const float* __restrict__ Gw,
                  const float* __restrict__ Uw,
                  unsigned short* __restrict__ inter,
                  const float* __restrict__ gs_p,
                  const float* __restrict__ us_p,
                  int K, int I) {
    __shared__ unsigned short As[BM * BK];
    __shared__ unsigned short Bg[BM * BK];
    __shared__ unsigned short Bu[BM * BK];

    const int tid = threadIdx.x;
    const int m_base = blockIdx.x * BM;
    const int nb = blockIdx.y * BM;

    f32x4 accg[4][4], accu[4][4];
    const f32x4 z = {0.0f, 0.0f, 0.0f, 0.0f};
#pragma unroll
    for (int i = 0; i < 4; ++i)
#pragma unroll
        for (int j = 0; j < 4; ++j) { accg[i][j] = z; accu[i][j] = z; }

    const int lane = tid & 63;
    const int wid = tid >> 6;
    const int wm = (wid >> 1) * 64;
    const int wn = (wid & 1) * 64;
    const int fr = lane & 15;

    const int c0 = tid, c1 = tid + 256;
    const int r0 = c0 >> 2, r1 = c1 >> 2;
    const int kc0 = (((c0 & 3) ^ ((c0 >> 3) & 3)) << 3);
    const int kc1 = (((c1 & 3) ^ ((c1 >> 3) & 3)) << 3);
    const int ca = (((lane >> 4) ^ ((fr >> 1) & 3)) << 3);

    const float* Gt = Gw + (size_t)nb * K;
    const float* Ut = Uw + (size_t)nb * K;

    for (int k0 = 0; k0 < K; k0 += BK) {
        GLOBAL_TO_LDS(Xb + (size_t)(m_base + r0) * K + (k0 + kc0), &As[c0 * 8]);
        GLOBAL_TO_LDS(Xb + (size_t)(m_base + r1) * K + (k0 + kc1), &As[c1 * 8]);
        STAGE_W_TILE(Gt, Bg);
        STAGE_W_TILE(Ut, Bu);
        __syncthreads();

        short8 a[4], bg[4], bu[4];
#pragma unroll
        for (int i = 0; i < 4; ++i) {
            a[i]  = *(const short8*)(&As[(wm + i * 16 + fr) * BK + ca]);
            bg[i] = *(const short8*)(&Bg[(wn + i * 16 + fr) * BK + ca]);
            bu[i] = *(const short8*)(&Bu[(wn + i * 16 + fr) * BK + ca]);
        }
#pragma unroll
        for (int mi = 0; mi < 4; ++mi)
#pragma unroll
            for (int ni = 0; ni < 4; ++ni) {
                accg[mi][ni] = __builtin_amdgcn_mfma_f32_16x16x32_bf16(
                    a[mi], bg[ni], accg[mi][ni], 0, 0, 0);
                accu[mi][ni] = __builtin_amdgcn_mfma_f32_16x16x32_bf16(
                    a[mi], bu[ni], accu[mi][ni], 0, 0, 0);
            }
        __syncthreads();
    }

    const float gsc = *gs_p;
    const float usc = *us_p;
    const int row0 = m_base + wm + (lane >> 4) * 4;
    const int col0 = nb + wn + fr;
#pragma unroll
    for (int mi = 0; mi < 4; ++mi)
#pragma unroll
        for (int ni = 0; ni < 4; ++ni)
#pragma unroll
            for (int r = 0; r < 4; ++r) {
                float g = accg[mi][ni][r] * gsc;
                float u = accu[mi][ni][r] * usc;
                float s = g / (1.0f + __expf(-g));   // silu
                inter[(size_t)(row0 + mi * 16 + r) * I + (col0 + ni * 16)] =
                    f2bf(s * u);
            }
}

// Down GEMM, BN=256 as two 128-col B tiles sharing the A tile; B fp32 inline-cvt.
// A=inter[M][K=I] bf16 (LDS-DMA), Dw=[rows][K] fp32; out[M][H] fp32.
__global__ __launch_bounds__(256, 2)
void gemm2_down(const unsigned short* __restrict__ Ab,
                const float* __restrict__ Dw,
                float* __restrict__ out,
                const float* __restrict__ ds_p,
                int K, int H) {
    __shared__ unsigned short As[BM * BK];
    __shared__ unsigned short B0[BM * BK];
    __shared__ unsigned short B1[BM * BK];

    const int tid = threadIdx.x;
    const int m_base = blockIdx.x * BM;
    const int nb = blockIdx.y * 256;

    f32x4 acc0[4][4], acc1[4][4];
    const f32x4 z = {0.0f, 0.0f, 0.0f, 0.0f};
#pragma unroll
    for (int i = 0; i < 4; ++i)
#pragma unroll
        for (int j = 0; j < 4; ++j) { acc0[i][j] = z; acc1[i][j] = z; }

    const int lane = tid & 63;
    const int wid = tid >> 6;
    const int wm = (wid >> 1) * 64;
    const int wn = (wid & 1) * 64;
    const int fr = lane & 15;

    const int c0 = tid, c1 = tid + 256;
    const int r0 = c0 >> 2, r1 = c1 >> 2;
    const int kc0 = (((c0 & 3) ^ ((c0 >> 3) & 3)) << 3);
    const int kc1 = (((c1 & 3) ^ ((c1 >> 3) & 3)) << 3);
    const int ca = (((lane >> 4) ^ ((fr >> 1) & 3)) << 3);

    const float* D0 = Dw + (size_t)nb * K;
    const float* D1 = Dw + (size_t)(nb + BM) * K;

    for (int k0 = 0; k0 < K; k0 += BK) {
        GLOBAL_TO_LDS(Ab + (size_t)(m_base + r0) * K + (k0 + kc0), &As[c0 * 8]);
        GLOBAL_TO_LDS(Ab + (size_t)(m_base + r1) * K + (k0 + kc1), &As[c1 * 8]);
        STAGE_W_TILE(D0, B0);
        STAGE_W_TILE(D1, B1);
        __syncthreads();

        short8 a[4], b0[4], b1[4];
#pragma unroll
        for (int i = 0; i < 4; ++i) {
            a[i]  = *(const short8*)(&As[(wm + i * 16 + fr) * BK + ca]);
            b0[i] = *(const short8*)(&B0[(wn + i * 16 + fr) * BK + ca]);
            b1[i] = *(const short8*)(&B1[(wn + i * 16 + fr) * BK + ca]);
        }
#pragma unroll
        for (int mi = 0; mi < 4; ++mi)
#pragma unroll
            for (int ni = 0; ni < 4; ++ni) {
                acc0[mi][ni] = __builtin_amdgcn_mfma_f32_16x16x32_bf16(
                    a[mi], b0[ni], acc0[mi][ni], 0, 0, 0);
                acc1[mi][ni] = __builtin_amdgcn_mfma_f32_16x16x32_bf16(
                    a[mi], b1[ni], acc1[mi][ni], 0, 0, 0);
            }
        __syncthreads();
    }

    const float dsc = *ds_p;
    const int row0 = m_base + wm + (lane >> 4) * 4;
    const int colA = nb + wn + fr;
    const int colB = colA + BM;
#pragma unroll
    for (int mi = 0; mi < 4; ++mi)
#pragma unroll
        for (int ni = 0; ni < 4; ++ni)
#pragma unroll
            for (int r = 0; r < 4; ++r) {
                const size_t rowoff = (size_t)(row0 + mi * 16 + r) * H;
                out[rowoff + (colA + ni * 16)] = acc0[mi][ni][r] * dsc;
                out[rowoff + (colB + ni * 16)] = acc1[mi][ni][r] * dsc;
            }
}

extern "C" void kernel_launch(void* const* d_in, const int* in_sizes, int n_in,
                              void* d_out, int out_size, void* d_ws, size_t ws_size,
                              hipStream_t stream) {
    (void)in_sizes; (void)n_in; (void)out_size;
    const float* x  = (const float*)d_in[0];
    const float* gw = (const float*)d_in[1];
    const float* uw = (const float*)d_in[2];
    const float* dw = (const float*)d_in[3];
    const float* gs = (const float*)d_in[4];
    const float* us = (const float*)d_in[5];
    const float* ds = (const float*)d_in[6];
    float* out = (float*)d_out;

    const long M = 4096;    // BATCH*SEQ
    const long Kh = 4096;   // HIDDEN
    const long I = 11008;   // INTER
    const long H = 4096;

    char* ws = (char*)d_ws;
    unsigned short* Xb = (unsigned short*)ws;                       // M*Kh bf16
    unsigned short* inter = (unsigned short*)(ws + M * Kh * 2);     // M*I bf16
    const size_t used = (size_t)M * Kh * 2 + (size_t)M * I * 2;     // ~124 MB
    if (ws_size < used) return;   // ws too small -> visible fail

    // ---- x -> bf16 ----
    {
        long n4 = M * Kh / 4;
        cvt_f32_bf16<<<dim3((unsigned)((n4 + 255) / 256)), dim3(256), 0, stream>>>(
            (const fvec4*)x, (usvec4*)Xb, n4);
    }

    // ---- gemm1: gate/up fused, weights fp32 converted in staging ----
    gemm1_swiglu<<<dim3((unsigned)(M / BM), (unsigned)(I / BM)), dim3(256), 0, stream>>>(
        Xb, gw, uw, inter, gs, us, (int)Kh, (int)I);

    // ---- gemm2: down, weights fp32 converted in staging ----
    gemm2_down<<<dim3((unsigned)(M / BM), (unsigned)(H / 256)), dim3(256), 0, stream>>>(
        inter, dw, out, ds, (int)I, (int)H);
}